// Round 7
// baseline (186.943 us; speedup 1.0000x reference)
//
#include <hip/hip_runtime.h>
#include <hip/hip_bf16.h>

// Round 7:
// - cvt kernel removed: qkv_gemm stages x as fp32 and converts to bf16 at
//   ds_write time (register-staged pipeline absorbs it; numerics identical).
// - attn: 128 q-rows/block (2 subtiles/wave sharing K/V fragments -> LDS
//   fragment traffic per q-row halved), register-staged K/V with lgkm-only
//   barriers (no vmcnt(0) drain), balanced qtj pairing, 512 blocks.
// - out_gemm unchanged from round 6.

typedef __bf16 bf16_t;
typedef __bf16 bf16x4 __attribute__((ext_vector_type(4)));
typedef __bf16 bf16x8 __attribute__((ext_vector_type(8)));
typedef float f32x4 __attribute__((ext_vector_type(4)));

#define AS_GLOBAL __attribute__((address_space(1)))
#define AS_LDS    __attribute__((address_space(3)))

// Barrier that drains LDS ops only -- leaves global loads in flight.
__device__ __forceinline__ void barrier_lgkm() {
    asm volatile("s_waitcnt lgkmcnt(0)\n\ts_barrier" ::: "memory");
}

__device__ __forceinline__ bf16x8 cvt_bf8(float4 lo, float4 hi) {
    bf16x8 r;
    r[0] = (bf16_t)lo.x; r[1] = (bf16_t)lo.y; r[2] = (bf16_t)lo.z; r[3] = (bf16_t)lo.w;
    r[4] = (bf16_t)hi.x; r[5] = (bf16_t)hi.y; r[6] = (bf16_t)hi.z; r[7] = (bf16_t)hi.w;
    return r;
}

// ---------------- 4x fp32 [K,N] -> bf16 transposed [N,K], fused ----------------
__global__ __launch_bounds__(256) void transpose_cvt4(
    const float* __restrict__ W0, const float* __restrict__ W1,
    const float* __restrict__ W2, const float* __restrict__ W3,
    bf16_t* __restrict__ outbase) {
    __shared__ bf16_t T[64][65];
    int t = threadIdx.x;
    int k0 = blockIdx.x * 64, n0 = blockIdx.y * 64, z = blockIdx.z;
    const float* W = (z == 0) ? W0 : (z == 1) ? W1 : (z == 2) ? W2 : W3;
    bf16_t* WT = outbase + (size_t)z * 1048576;
#pragma unroll
    for (int c = 0; c < 4; c++) {
        int idx = c * 256 + t;
        int row = idx >> 4;
        int col4 = (idx & 15) * 4;
        float4 v = *(const float4*)(W + (k0 + row) * 1024 + n0 + col4);
        T[row][col4 + 0] = (bf16_t)v.x;
        T[row][col4 + 1] = (bf16_t)v.y;
        T[row][col4 + 2] = (bf16_t)v.z;
        T[row][col4 + 3] = (bf16_t)v.w;
    }
    __syncthreads();
#pragma unroll
    for (int c = 0; c < 4; c++) {
        int idx = c * 256 + t;
        int nrow = idx >> 4;
        int kc4 = (idx & 15) * 4;
        bf16x4 o;
        o[0] = T[kc4 + 0][nrow];
        o[1] = T[kc4 + 1][nrow];
        o[2] = T[kc4 + 2][nrow];
        o[3] = T[kc4 + 3][nrow];
        *(bf16x4*)(WT + (n0 + nrow) * 1024 + k0 + kc4) = o;
    }
}

// ---------------- fused QKV GEMM (register-staged; A = fp32 x) ----------------
// z=0: Q natural [B,H,S,64]
// z=1: K tiled-swizzled: per (b,h): [kt][row=s%64][chunk^(row%8)][d%8]
// z=2: V^T tiled-swizzled: per (b,h): [kt][d][chunk^(d%8)][s%8]
__global__ __launch_bounds__(256) void qkv_gemm(
    const float* __restrict__ X,
    const bf16_t* __restrict__ WqT, const bf16_t* __restrict__ WkT,
    const bf16_t* __restrict__ WvT,
    bf16_t* __restrict__ Qo, bf16_t* __restrict__ Ko, bf16_t* __restrict__ Vo) {
    const int KD = 1024;
    __shared__ __align__(16) bf16_t As[2][4096];
    __shared__ __align__(16) bf16_t Bs[2][4096];
    int tid = threadIdx.x;
    int wave = tid >> 6, lane = tid & 63;
    int quad = lane >> 4, l16 = lane & 15;
    int wm = wave >> 1, wn = wave & 1;
    int z = blockIdx.z;
    const bf16_t* BT = (z == 0) ? WqT : (z == 1) ? WkT : WvT;
    int m0 = blockIdx.x * 128;
    int n0 = blockIdx.y * 128;

    int r = tid >> 2;
    int c8 = (((tid & 3) ^ ((tid >> 3) & 3))) * 8;  // staged chunk swizzle
    const float*  gA0 = X + (size_t)(m0 + r) * KD + c8;
    const float*  gA1 = X + (size_t)(m0 + 64 + r) * KD + c8;
    const bf16_t* gB0 = BT + (size_t)(n0 + r) * KD + c8;
    const bf16_t* gB1 = BT + (size_t)(n0 + 64 + r) * KD + c8;

    f32x4 acc[4][4];
#pragma unroll
    for (int i = 0; i < 4; i++)
#pragma unroll
        for (int j = 0; j < 4; j++) acc[i][j] = (f32x4){0.f, 0.f, 0.f, 0.f};

    // prologue: tile 0 straight to LDS buf0; tile 1 into stage regs
    float4 fa0l = *(const float4*)gA0, fa0h = *(const float4*)(gA0 + 4);
    float4 fa1l = *(const float4*)gA1, fa1h = *(const float4*)(gA1 + 4);
    int4 sb0 = *(const int4*)gB0, sb1 = *(const int4*)gB1;
    *(bf16x8*)(As[0] + tid * 8) = cvt_bf8(fa0l, fa0h);
    *(bf16x8*)(As[0] + 2048 + tid * 8) = cvt_bf8(fa1l, fa1h);
    *(int4*)(Bs[0] + tid * 8) = sb0;
    *(int4*)(Bs[0] + 2048 + tid * 8) = sb1;
    fa0l = *(const float4*)(gA0 + 32); fa0h = *(const float4*)(gA0 + 36);
    fa1l = *(const float4*)(gA1 + 32); fa1h = *(const float4*)(gA1 + 36);
    sb0 = *(const int4*)(gB0 + 32); sb1 = *(const int4*)(gB1 + 32);

    int csw = (quad ^ ((l16 >> 1) & 3)) * 8;
#pragma unroll 1
    for (int kk = 0; kk < 32; kk += 2) {
        // ---- even: compute kk from buf0; stage kk+1 -> buf1; load kk+2
        barrier_lgkm();
        bf16x8 af[4], bfr[4];
#pragma unroll
        for (int mt = 0; mt < 4; mt++)
            af[mt] = *(const bf16x8*)(As[0] + (wm * 64 + mt * 16 + l16) * 32 + csw);
#pragma unroll
        for (int nt = 0; nt < 4; nt++)
            bfr[nt] = *(const bf16x8*)(Bs[0] + (wn * 64 + nt * 16 + l16) * 32 + csw);
        *(bf16x8*)(As[1] + tid * 8) = cvt_bf8(fa0l, fa0h);
        *(bf16x8*)(As[1] + 2048 + tid * 8) = cvt_bf8(fa1l, fa1h);
        *(int4*)(Bs[1] + tid * 8) = sb0;
        *(int4*)(Bs[1] + 2048 + tid * 8) = sb1;
        if (kk + 2 < 32) {
            int k0 = (kk + 2) * 32;
            fa0l = *(const float4*)(gA0 + k0); fa0h = *(const float4*)(gA0 + k0 + 4);
            fa1l = *(const float4*)(gA1 + k0); fa1h = *(const float4*)(gA1 + k0 + 4);
            sb0 = *(const int4*)(gB0 + k0); sb1 = *(const int4*)(gB1 + k0);
        }
        if (z == 2) {
#pragma unroll
            for (int mt = 0; mt < 4; mt++)
#pragma unroll
                for (int nt = 0; nt < 4; nt++)
                    acc[mt][nt] = __builtin_amdgcn_mfma_f32_16x16x32_bf16(
                        bfr[nt], af[mt], acc[mt][nt], 0, 0, 0);
        } else {
#pragma unroll
            for (int mt = 0; mt < 4; mt++)
#pragma unroll
                for (int nt = 0; nt < 4; nt++)
                    acc[mt][nt] = __builtin_amdgcn_mfma_f32_16x16x32_bf16(
                        af[mt], bfr[nt], acc[mt][nt], 0, 0, 0);
        }
        // ---- odd: compute kk+1 from buf1; stage kk+2 -> buf0; load kk+3
        barrier_lgkm();
#pragma unroll
        for (int mt = 0; mt < 4; mt++)
            af[mt] = *(const bf16x8*)(As[1] + (wm * 64 + mt * 16 + l16) * 32 + csw);
#pragma unroll
        for (int nt = 0; nt < 4; nt++)
            bfr[nt] = *(const bf16x8*)(Bs[1] + (wn * 64 + nt * 16 + l16) * 32 + csw);
        if (kk + 2 < 32) {
            *(bf16x8*)(As[0] + tid * 8) = cvt_bf8(fa0l, fa0h);
            *(bf16x8*)(As[0] + 2048 + tid * 8) = cvt_bf8(fa1l, fa1h);
            *(int4*)(Bs[0] + tid * 8) = sb0;
            *(int4*)(Bs[0] + 2048 + tid * 8) = sb1;
            if (kk + 3 < 32) {
                int k0 = (kk + 3) * 32;
                fa0l = *(const float4*)(gA0 + k0); fa0h = *(const float4*)(gA0 + k0 + 4);
                fa1l = *(const float4*)(gA1 + k0); fa1h = *(const float4*)(gA1 + k0 + 4);
                sb0 = *(const int4*)(gB0 + k0); sb1 = *(const int4*)(gB1 + k0);
            }
        }
        if (z == 2) {
#pragma unroll
            for (int mt = 0; mt < 4; mt++)
#pragma unroll
                for (int nt = 0; nt < 4; nt++)
                    acc[mt][nt] = __builtin_amdgcn_mfma_f32_16x16x32_bf16(
                        bfr[nt], af[mt], acc[mt][nt], 0, 0, 0);
        } else {
#pragma unroll
            for (int mt = 0; mt < 4; mt++)
#pragma unroll
                for (int nt = 0; nt < 4; nt++)
                    acc[mt][nt] = __builtin_amdgcn_mfma_f32_16x16x32_bf16(
                        af[mt], bfr[nt], acc[mt][nt], 0, 0, 0);
        }
    }

    if (z == 0) {
#pragma unroll
        for (int mt = 0; mt < 4; mt++) {
            int mg_base = m0 + wm * 64 + mt * 16 + quad * 4;
#pragma unroll
            for (int nt = 0; nt < 4; nt++) {
                int ng = n0 + wn * 64 + nt * 16 + l16;
                int h = ng >> 6, d = ng & 63;
#pragma unroll
                for (int rr = 0; rr < 4; rr++) {
                    int mg = mg_base + rr;
                    int b = mg >> 11, s = mg & 2047;
                    Qo[(((size_t)(b * 16 + h) * 2048) + s) * 64 + d] =
                        (bf16_t)acc[mt][nt][rr];
                }
            }
        }
    } else if (z == 1) {
#pragma unroll
        for (int mt = 0; mt < 4; mt++) {
            int mg_base = m0 + wm * 64 + mt * 16 + quad * 4;
#pragma unroll
            for (int nt = 0; nt < 4; nt++) {
                int ng = n0 + wn * 64 + nt * 16 + l16;
                int h = ng >> 6, dd = ng & 63;
#pragma unroll
                for (int rr = 0; rr < 4; rr++) {
                    int mg = mg_base + rr;
                    int b = mg >> 11, sl = mg & 2047;
                    int kt = sl >> 6, row = sl & 63;
                    int cc = (dd >> 3) ^ (row & 7);
                    Ko[(size_t)(b * 16 + h) * 131072 + kt * 4096 + row * 64 +
                       cc * 8 + (dd & 7)] = (bf16_t)acc[mt][nt][rr];
                }
            }
        }
    } else {
#pragma unroll
        for (int mt = 0; mt < 4; mt++) {
            int sg = m0 + wm * 64 + mt * 16 + l16;
            int b = sg >> 11, sl = sg & 2047;
            int kt = sl >> 6, srow = sl & 63;
#pragma unroll
            for (int nt = 0; nt < 4; nt++) {
                int dg_base = n0 + wn * 64 + nt * 16 + quad * 4;
#pragma unroll
                for (int rr = 0; rr < 4; rr++) {
                    int dg = dg_base + rr;
                    int h = dg >> 6, dd = dg & 63;
                    int cc = (srow >> 3) ^ (dd & 7);
                    Vo[(size_t)(b * 16 + h) * 131072 + kt * 4096 + dd * 64 +
                       cc * 8 + (srow & 7)] = (bf16_t)acc[mt][nt][rr];
                }
            }
        }
    }
}

// ---------------- flash attention v5: 128 q-rows/block, reg-staged K/V ------
__device__ __forceinline__ float exp_pwrite(f32x4 sc[4], bf16_t* Ps,
                                            int wave, int quad, int l16) {
    float part = 0.f;
    int rowbase = (wave * 16 + l16) * 64;
    int gran = (quad & 1) * 4;
    int chi = quad >> 1;
#pragma unroll
    for (int nt = 0; nt < 4; nt++) {
        f32x4 p;
#pragma unroll
        for (int rr = 0; rr < 4; rr++) {
            p[rr] = __builtin_amdgcn_exp2f(sc[nt][rr]);
            part += p[rr];
        }
        bf16x4 pb;
#pragma unroll
        for (int rr = 0; rr < 4; rr++) pb[rr] = (bf16_t)p[rr];
        int cc = (nt * 2 + chi) ^ (l16 & 7);
        *(bf16x4*)(Ps + rowbase + cc * 8 + gran) = pb;
    }
    part += __shfl_xor(part, 16);
    part += __shfl_xor(part, 32);
    return part;
}

// grid: 512 blocks (dim3(32,16)). f = x + 32*y; g=f>>8, s=f&255.
// qtj = g ? 15-(s&15) : s&15 (128-row q-tile); bh = (s>>4) + 16*g.
// Co-resident pair {f, f+256}: qtj {i, 15-i} -> per-CU iters const (34).
__global__ __launch_bounds__(256) void attn(
    const bf16_t* __restrict__ Q, const bf16_t* __restrict__ Kt,
    const bf16_t* __restrict__ Vt, bf16_t* __restrict__ ctx) {
    const int S = 2048;
    __shared__ __align__(16) bf16_t Ks[2][4096];
    __shared__ __align__(16) bf16_t Vs[2][4096];
    __shared__ __align__(16) bf16_t Ps[2][4096];
    int tid = threadIdx.x, wave = tid >> 6, lane = tid & 63;
    int quad = lane >> 4, l16 = lane & 15;

    int f = blockIdx.x + 32 * blockIdx.y;
    int g = f >> 8, s = f & 255;
    int qtj = g ? (15 - (s & 15)) : (s & 15);
    int bh = (s >> 4) + 16 * g;
    int h = bh & 15, b = bh >> 4;
    int q0 = qtj * 128;

    const bf16_t* Qbh = Q + (size_t)bh * S * 64;
    const bf16_t* Kbh = Kt + (size_t)bh * 131072;
    const bf16_t* Vbh = Vt + (size_t)bh * 131072;

    const float qs = 0.125f * 1.44269504f;
    bf16x8 aQ[2][2];  // [subtile][ks]
#pragma unroll
    for (int sub = 0; sub < 2; sub++) {
        const bf16_t* rq = Qbh + (size_t)(q0 + sub * 64 + wave * 16 + l16) * 64;
#pragma unroll
        for (int ks = 0; ks < 2; ks++) {
            bf16x8 t = *(const bf16x8*)(rq + ks * 32 + quad * 8);
#pragma unroll
            for (int j = 0; j < 8; j++) t[j] = (bf16_t)((float)t[j] * qs);
            aQ[sub][ks] = t;
        }
    }

    float L[2] = {0.f, 0.f};
    f32x4 O[2][4];
#pragma unroll
    for (int sub = 0; sub < 2; sub++)
#pragma unroll
        for (int i = 0; i < 4; i++) O[sub][i] = (f32x4){0.f, 0.f, 0.f, 0.f};

    int tmax = 2 * qtj + 2;
    // prologue: tile 0 -> LDS[0]; tile 1 -> stage regs (tmax >= 2 always)
    int4 ska = *(const int4*)(Kbh + tid * 8);
    int4 skb = *(const int4*)(Kbh + 2048 + tid * 8);
    int4 sva = *(const int4*)(Vbh + tid * 8);
    int4 svb = *(const int4*)(Vbh + 2048 + tid * 8);
    *(int4*)(Ks[0] + tid * 8) = ska; *(int4*)(Ks[0] + 2048 + tid * 8) = skb;
    *(int4*)(Vs[0] + tid * 8) = sva; *(int4*)(Vs[0] + 2048 + tid * 8) = svb;
    ska = *(const int4*)(Kbh + 4096 + tid * 8);
    skb = *(const int4*)(Kbh + 6144 + tid * 8);
    sva = *(const int4*)(Vbh + 4096 + tid * 8);
    svb = *(const int4*)(Vbh + 6144 + tid * 8);

#pragma unroll 1
    for (int kt = 0; kt < tmax; kt++) {
        int cur = kt & 1;
        barrier_lgkm();
        // fragment reads from current buffers
        bf16x8 kf[4][2], vf[4][2];
#pragma unroll
        for (int nt = 0; nt < 4; nt++) {
            const bf16_t* krow = Ks[cur] + (nt * 16 + l16) * 64;
            const bf16_t* vrow = Vs[cur] + (nt * 16 + l16) * 64;
#pragma unroll
            for (int ks = 0; ks < 2; ks++) {
                int csw = ((ks * 4 + quad) ^ (l16 & 7)) * 8;
                kf[nt][ks] = *(const bf16x8*)(krow + csw);
                vf[nt][ks] = *(const bf16x8*)(vrow + csw);
            }
        }
        // stage tile kt+1 into the other buffer
        if (kt + 1 < tmax) {
            *(int4*)(Ks[cur ^ 1] + tid * 8) = ska;
            *(int4*)(Ks[cur ^ 1] + 2048 + tid * 8) = skb;
            *(int4*)(Vs[cur ^ 1] + tid * 8) = sva;
            *(int4*)(Vs[cur ^ 1] + 2048 + tid * 8) = svb;
        }
        // load tile kt+2 into stage regs
        if (kt + 2 < tmax) {
            const bf16_t* kg = Kbh + (kt + 2) * 4096;
            const bf16_t* vg = Vbh + (kt + 2) * 4096;
            ska = *(const int4*)(kg + tid * 8);
            skb = *(const int4*)(kg + 2048 + tid * 8);
            sva = *(const int4*)(vg + tid * 8);
            svb = *(const int4*)(vg + 2048 + tid * 8);
        }

        bool do_lo = (kt < tmax - 1);  // last tile's keys all exceed lo rows
        // S^T = K @ Q^T; lane: key = kt*64+nt*16+quad*4+rr, q = l16
        if (do_lo) {
            f32x4 sc[4];
#pragma unroll
            for (int nt = 0; nt < 4; nt++) {
                f32x4 ss = (f32x4){0.f, 0.f, 0.f, 0.f};
                ss = __builtin_amdgcn_mfma_f32_16x16x32_bf16(kf[nt][0], aQ[0][0], ss, 0, 0, 0);
                ss = __builtin_amdgcn_mfma_f32_16x16x32_bf16(kf[nt][1], aQ[0][1], ss, 0, 0, 0);
                sc[nt] = ss;
            }
            if (kt == tmax - 2) {  // lo diagonal
                int qg = q0 + wave * 16 + l16;
#pragma unroll
                for (int nt = 0; nt < 4; nt++)
#pragma unroll
                    for (int rr = 0; rr < 4; rr++)
                        if (kt * 64 + nt * 16 + quad * 4 + rr > qg) sc[nt][rr] = -1e30f;
            }
            L[0] += exp_pwrite(sc, Ps[0], wave, quad, l16);
        }
        {
            f32x4 sc[4];
#pragma unroll
            for (int nt = 0; nt < 4; nt++) {
                f32x4 ss = (f32x4){0.f, 0.f, 0.f, 0.f};
                ss = __builtin_amdgcn_mfma_f32_16x16x32_bf16(kf[nt][0], aQ[1][0], ss, 0, 0, 0);
                ss = __builtin_amdgcn_mfma_f32_16x16x32_bf16(kf[nt][1], aQ[1][1], ss, 0, 0, 0);
                sc[nt] = ss;
            }
            if (kt == tmax - 1) {  // hi diagonal
                int qg = q0 + 64 + wave * 16 + l16;
#pragma unroll
                for (int nt = 0; nt < 4; nt++)
#pragma unroll
                    for (int rr = 0; rr < 4; rr++)
                        if (kt * 64 + nt * 16 + quad * 4 + rr > qg) sc[nt][rr] = -1e30f;
            }
            L[1] += exp_pwrite(sc, Ps[1], wave, quad, l16);
        }

        // O += P @ V (per-wave Ps slab; wave-local LDS is in-order)
#pragma unroll
        for (int ks = 0; ks < 2; ks++) {
            int csw = ((ks * 4 + quad) ^ (l16 & 7)) * 8;
            bf16x8 aPhi = *(const bf16x8*)(Ps[1] + (wave * 16 + l16) * 64 + csw);
            bf16x8 aPlo;
            if (do_lo) aPlo = *(const bf16x8*)(Ps[0] + (wave * 16 + l16) * 64 + csw);
#pragma unroll
            for (int nt = 0; nt < 4; nt++) {
                O[1][nt] = __builtin_amdgcn_mfma_f32_16x16x32_bf16(aPhi, vf[nt][ks],
                                                                   O[1][nt], 0, 0, 0);
                if (do_lo)
                    O[0][nt] = __builtin_amdgcn_mfma_f32_16x16x32_bf16(aPlo, vf[nt][ks],
                                                                       O[0][nt], 0, 0, 0);
            }
        }
    }

#pragma unroll
    for (int sub = 0; sub < 2; sub++) {
        float il[4];
#pragma unroll
        for (int rr = 0; rr < 4; rr++) il[rr] = 1.f / __shfl(L[sub], quad * 4 + rr);
#pragma unroll
        for (int nt = 0; nt < 4; nt++) {
#pragma unroll
            for (int rr = 0; rr < 4; rr++) {
                int qoff = q0 + sub * 64 + wave * 16 + quad * 4 + rr;
                int col = h * 64 + nt * 16 + l16;
                ctx[(size_t)(b * 2048 + qoff) * 1024 + col] =
                    (bf16_t)(O[sub][nt][rr] * il[rr]);
            }
        }
    }
}

// ---------------- out projection (register-staged pipeline, 64x128) ----------------
__global__ __launch_bounds__(256) void out_gemm(
    const bf16_t* __restrict__ A, const bf16_t* __restrict__ BT,
    const float* __restrict__ bias, float* __restrict__ Cout) {
    const int KD = 1024;
    __shared__ __align__(16) bf16_t As[2][2048];
    __shared__ __align__(16) bf16_t Bs[2][4096];
    int tid = threadIdx.x;
    int wave = tid >> 6, lane = tid & 63;
    int quad = lane >> 4, l16 = lane & 15;
    int wm = wave >> 1, wn = wave & 1;
    int m0 = blockIdx.x * 64;
    int n0 = blockIdx.y * 128;

    int r = tid >> 2;
    int c8 = (((tid & 3) ^ ((tid >> 3) & 3))) * 8;
    const bf16_t* gA  = A + (size_t)(m0 + r) * KD + c8;
    const bf16_t* gB0 = BT + (size_t)(n0 + r) * KD + c8;
    const bf16_t* gB1 = BT + (size_t)(n0 + 64 + r) * KD + c8;

    f32x4 acc[2][4];
#pragma unroll
    for (int i = 0; i < 2; i++)
#pragma unroll
        for (int j = 0; j < 4; j++) acc[i][j] = (f32x4){0.f, 0.f, 0.f, 0.f};

    int4 sa = *(const int4*)gA;
    int4 sb0 = *(const int4*)gB0, sb1 = *(const int4*)gB1;
    *(int4*)(As[0] + tid * 8) = sa;
    *(int4*)(Bs[0] + tid * 8) = sb0;
    *(int4*)(Bs[0] + 2048 + tid * 8) = sb1;
    sa = *(const int4*)(gA + 32);
    sb0 = *(const int4*)(gB0 + 32); sb1 = *(const int4*)(gB1 + 32);

    int csw = (quad ^ ((l16 >> 1) & 3)) * 8;
#pragma unroll 1
    for (int kk = 0; kk < 32; kk += 2) {
        barrier_lgkm();
        bf16x8 af[2], bfr[4];
#pragma unroll
        for (int mt = 0; mt < 2; mt++)
            af[mt] = *(const bf16x8*)(As[0] + (wm * 32 + mt * 16 + l16) * 32 + csw);
#pragma unroll
        for (int nt = 0; nt < 4; nt++)
            bfr[nt] = *(const bf16x8*)(Bs[0] + (wn * 64 + nt * 16 + l16) * 32 + csw);
        *(int4*)(As[1] + tid * 8) = sa;
        *(int4*)(Bs[1] + tid * 8) = sb0;
        *(int4*)(Bs[1] + 2048 + tid * 8) = sb1;
        if (kk + 2 < 32) {
            int k0 = (kk + 2) * 32;
            sa = *(const int4*)(gA + k0);
            sb0 = *(const int4*)(gB0 + k0); sb1 = *(const int4*)(gB1 + k0);
        }
#pragma unroll
        for (int mt = 0; mt < 2; mt++)
#pragma unroll
            for (int nt = 0; nt < 4; nt++)
                acc[mt][nt] = __builtin_amdgcn_mfma_f32_16x16x32_bf16(af[mt], bfr[nt],
                                                                      acc[mt][nt], 0, 0, 0);
        barrier_lgkm();
#pragma unroll
        for (int mt = 0; mt < 2; mt++)
            af[mt] = *(const bf16x8*)(As[1] + (wm * 32 + mt * 16 + l16) * 32 + csw);
#pragma unroll
        for (int nt = 0; nt < 4; nt++)
            bfr[nt] = *(const bf16x8*)(Bs[1] + (wn * 64 + nt * 16 + l16) * 32 + csw);
        if (kk + 2 < 32) {
            *(int4*)(As[0] + tid * 8) = sa;
            *(int4*)(Bs[0] + tid * 8) = sb0;
            *(int4*)(Bs[0] + 2048 + tid * 8) = sb1;
            if (kk + 3 < 32) {
                int k0 = (kk + 3) * 32;
                sa = *(const int4*)(gA + k0);
                sb0 = *(const int4*)(gB0 + k0); sb1 = *(const int4*)(gB1 + k0);
            }
        }
#pragma unroll
        for (int mt = 0; mt < 2; mt++)
#pragma unroll
            for (int nt = 0; nt < 4; nt++)
                acc[mt][nt] = __builtin_amdgcn_mfma_f32_16x16x32_bf16(af[mt], bfr[nt],
                                                                      acc[mt][nt], 0, 0, 0);
    }

#pragma unroll
    for (int mt = 0; mt < 2; mt++) {
        int mg_base = m0 + wm * 32 + mt * 16 + quad * 4;
#pragma unroll
        for (int nt = 0; nt < 4; nt++) {
            int ng = n0 + wn * 64 + nt * 16 + l16;
            float bv = bias[ng];
#pragma unroll
            for (int rr = 0; rr < 4; rr++) {
                int mg = mg_base + rr;
                Cout[(size_t)mg * 1024 + ng] = acc[mt][nt][rr] + bv;
            }
        }
    }
}

extern "C" void kernel_launch(void* const* d_in, const int* in_sizes, int n_in,
                              void* d_out, int out_size, void* d_ws, size_t ws_size,
                              hipStream_t stream) {
    const float* x  = (const float*)d_in[0];
    const float* Wq = (const float*)d_in[1];
    const float* Wk = (const float*)d_in[2];
    const float* Wv = (const float*)d_in[3];
    const float* Wo = (const float*)d_in[4];
    const float* bo = (const float*)d_in[5];
    float* out = (float*)d_out;
    char* ws = (char*)d_ws;

    bf16_t* WTs  = (bf16_t*)(ws + (8u << 20));          // 4x2 MB
    bf16_t* WqT  = WTs;
    bf16_t* WkT  = WTs + 1048576;
    bf16_t* WvT  = WTs + 2097152;
    bf16_t* WoT  = WTs + 3145728;
    bf16_t* Qb   = (bf16_t*)(ws + (16u << 20));         // 8 MB natural
    bf16_t* Kb   = (bf16_t*)(ws + (24u << 20));         // 8 MB tiled-swizzled
    bf16_t* Vb   = (bf16_t*)(ws + (32u << 20));         // 8 MB tiled-swizzled V^T
    bf16_t* ctxb = (bf16_t*)(ws + (40u << 20));         // 8 MB

    transpose_cvt4<<<dim3(16, 16, 4), 256, 0, stream>>>(Wq, Wk, Wv, Wo, WTs);
    qkv_gemm<<<dim3(32, 8, 3), 256, 0, stream>>>(x, WqT, WkT, WvT, Qb, Kb, Vb);
    attn<<<dim3(32, 16), 256, 0, stream>>>(Qb, Kb, Vb, ctxb);
    out_gemm<<<dim3(64, 8), 256, 0, stream>>>(ctxb, WoT, bo, out);
}